// Round 4
// baseline (611.619 us; speedup 1.0000x reference)
//
#include <hip/hip_runtime.h>

#define N_NODES 100000
#define M_PAD   100096      // 782 * 128
#define N_EDGES 1000000
#define K_TOT   320         // 128 (x) + 128 (agg_x) + 64 (agg_t)
#define NCHUNK  98          // ceil(100000/1024)

#define BM  128

#define XCONV_THREADS 1600000          // N_NODES*128/8 elems, 8 per thread
#define PREP_BLOCKS   6410             // (XCONV_THREADS + K_TOT*128)/256
#define HIST_BLOCKS   3907             // ceil(N_EDGES/256)

typedef __attribute__((ext_vector_type(8))) short bf16x8;
typedef __attribute__((ext_vector_type(4))) float f32x4;

__device__ __forceinline__ unsigned short f2bf(float f) {
    unsigned u = __float_as_uint(f);
    u += 0x7FFFu + ((u >> 16) & 1u);          // round-to-nearest-even
    return (unsigned short)(u >> 16);
}
__device__ __forceinline__ unsigned pack2(float a, float b) {
    return (unsigned)f2bf(a) | ((unsigned)f2bf(b) << 16);
}
__device__ __forceinline__ float bflo(unsigned v) { return __uint_as_float(v << 16); }
__device__ __forceinline__ float bfhi(unsigned v) { return __uint_as_float(v & 0xffff0000u); }

// global -> LDS direct DMA, 16 B per lane. Dest = wave-uniform base + lane*16.
__device__ __forceinline__ void gl_lds16(const void* g, void* l) {
    __builtin_amdgcn_global_load_lds(
        (const __attribute__((address_space(1))) unsigned*)g,
        (__attribute__((address_space(3))) unsigned*)l, 16, 0, 0);
}

// ---------------------------------------------------------------------------
// Fused prep + hist:
//   blocks [0, PREP_BLOCKS):  xb = bf16(x), Gtb[o][k] k-contig bf16, bias2
//   blocks [PREP_BLOCKS, +HIST_BLOCKS): edge histogram (hist pre-zeroed)
// ---------------------------------------------------------------------------
__global__ __launch_bounds__(256) void prep_hist_kernel(
        const float* __restrict__ x,
        const float* __restrict__ WSw,
        const float* __restrict__ WTw,
        const float* __restrict__ Tw,
        const float* __restrict__ WTb,
        const float* __restrict__ Tb,
        unsigned short* __restrict__ xb,
        unsigned short* __restrict__ Gtb,
        float* __restrict__ bias2,
        const int* __restrict__ ei,
        int* __restrict__ hist) {
    int b = blockIdx.x;
    int t = threadIdx.x;
    if (b >= PREP_BLOCKS) {
        int e = (b - PREP_BLOCKS) * 256 + t;
        if (e < N_EDGES) atomicAdd(&hist[ei[e]], 1);
        return;
    }
    int gid = b * 256 + t;
    if (gid < XCONV_THREADS) {
        const float4* p = (const float4*)x + (size_t)gid * 2;
        float4 u0 = p[0], u1 = p[1];
        uint4 w;
        w.x = pack2(u0.x, u0.y);
        w.y = pack2(u0.z, u0.w);
        w.z = pack2(u1.x, u1.y);
        w.w = pack2(u1.z, u1.w);
        *(uint4*)(xb + (size_t)gid * 8) = w;
    } else {
        int idx = gid - XCONV_THREADS;
        if (idx < K_TOT * 128) {
            int k = idx >> 7;
            int o = idx & 127;
            float v = (k < 128) ? WSw[o * 128 + k]
                    : (k < 256) ? WTw[o * 128 + (k - 128)]
                                : Tw[o * 64 + (k - 256)];
            Gtb[(size_t)o * K_TOT + k] = f2bf(v);
        }
        if (idx < 128) bias2[idx] = WTb[idx] + Tb[idx];
    }
}

// ---------------------------------------------------------------------------
// CSR build: scan (chunk-prefix folded into pass2) -> fill.
// fill bumps `offsets` in place; afterwards offsets[n] == end[n] and
// offsets[n-1] == beg[n] (CSR contiguity). deg[n] = offsets[n]-offsets[n-1].
// ---------------------------------------------------------------------------
__global__ __launch_bounds__(256) void scan_pass1(const int* __restrict__ hist,
                                                  int* __restrict__ chunksum) {
    __shared__ int ts[256];
    int b = blockIdx.x, t = threadIdx.x;
    int i = b * 1024 + t * 4;
    int s = 0;
#pragma unroll
    for (int j = 0; j < 4; ++j)
        if (i + j < N_NODES) s += hist[i + j];
    ts[t] = s;
    __syncthreads();
    for (int off = 128; off > 0; off >>= 1) {
        if (t < off) ts[t] += ts[t + off];
        __syncthreads();
    }
    if (t == 0) chunksum[b] = ts[0];
}

__global__ __launch_bounds__(256) void scan_pass2(const int* __restrict__ hist,
                                                  const int* __restrict__ csum,
                                                  int* __restrict__ offsets) {
    __shared__ int ts[256];
    __shared__ int cbase_s;
    int b = blockIdx.x, t = threadIdx.x;
    int i0 = b * 1024 + t * 4;
    int v[4];
    int s = 0;
#pragma unroll
    for (int j = 0; j < 4; ++j) {
        v[j] = (i0 + j < N_NODES) ? hist[i0 + j] : 0;
        s += v[j];
    }
    ts[t] = s;
    // wave 0: exclusive chunk base = sum csum[0..b)  (<=2 loads/lane, L2-hot)
    if (t < 64) {
        int cs = 0;
        for (int i = t; i < b; i += 64) cs += csum[i];
        for (int off = 32; off; off >>= 1) cs += __shfl_down(cs, off);
        if (t == 0) cbase_s = cs;
    }
    __syncthreads();
    for (int off = 1; off < 256; off <<= 1) {
        int add = (t >= off) ? ts[t - off] : 0;
        __syncthreads();
        ts[t] += add;
        __syncthreads();
    }
    int run = cbase_s + ts[t] - s;   // exclusive base for this thread
#pragma unroll
    for (int j = 0; j < 4; ++j) {
        if (i0 + j < N_NODES) offsets[i0 + j] = run;
        run += v[j];
    }
}

__global__ __launch_bounds__(256) void fill_kernel(const int* __restrict__ ei,
                                                   int* __restrict__ offsets,
                                                   unsigned long long* __restrict__ ec) {
    int e = blockIdx.x * 256 + threadIdx.x;
    if (e < N_EDGES) {
        int row = ei[e];
        int col = ei[N_EDGES + e];
        int pos = atomicAdd(&offsets[row], 1);
        ec[pos] = ((unsigned long long)(unsigned)col << 32) | (unsigned)e;
    }
}

// ---------------------------------------------------------------------------
// FUSED aggregate + GEMM. One block = 128 nodes.
// Phase 1 (agg): 8 waves x 16 nodes; gather xb rows (bf16) + tf rows (fp32),
//   accumulate fp32, pack2 -> bf16 into XOR-swizzled LDS (aggx 32KB, aggt
//   16KB). Identical arithmetic/rounding to the previous standalone agg ->
//   bit-identical result; saves the 77MB aggx/aggt/deg HBM round-trip.
// Phase 2 (gemm): out = relu([xb | aggx | aggt] @ Gtb^T + WSb + deg*bias2).
//   Chunks 0,1: A from gl_lds-staged xb (issued BEFORE phase 1 -> fully
//   hidden). Chunks 2,3,4: A straight from agg LDS. B staged per chunk.
//   deg recomputed from L2-hot offsets in the epilogue.
// LDS: 16+16+32+16 = 80 KB -> 2 blocks/CU.
// ---------------------------------------------------------------------------
__global__ __launch_bounds__(512, 4) void agg_gemm_kernel(
        const float* __restrict__ tf,
        const unsigned long long* __restrict__ ec,
        const int* __restrict__ offsets,   // post-fill: offsets[n] = end[n]
        const unsigned short* __restrict__ xb,
        const unsigned short* __restrict__ Gtb,
        const float* __restrict__ WSb,
        const float* __restrict__ bias2,
        float* __restrict__ out) {
    __shared__ unsigned short As[BM * 64];    // 16 KB, swizzled xb chunk
    __shared__ unsigned short Bs[BM * 64];    // 16 KB, swizzled Gtb chunk
    __shared__ unsigned aggx_lds[BM * 64];    // 32 KB: 128 rows x 64 u32 (128 bf16)
    __shared__ unsigned aggt_lds[BM * 32];    // 16 KB: 128 rows x 32 u32 (64 bf16)

    const unsigned* xw = (const unsigned*)xb;  // u32 view, row stride 64

    int t = threadIdx.x;
    int lane = t & 63;
    int wave = t >> 6;                         // 0..7
    int row0 = blockIdx.x * BM;

    // staging geometry (verified in r3): region r covers LDS rows 8r..8r+7;
    // lane: lr = row-in-region, lc = 16B slot; source col pre-swizzled.
    int lr = lane >> 3;
    int lc = lane & 7;
    int swz = ((lc ^ lr) << 4);

    // ---- issue chunk-0 staging now; completes under the agg phase
#pragma unroll
    for (int j = 0; j < 2; ++j) {
        int r = wave * 2 + j;                  // 0..15
        int row = r * 8 + lr;
        gl_lds16((const char*)xb + (size_t)(row0 + row) * 256 + swz,
                 (char*)As + r * 1024);
        gl_lds16((const char*)Gtb + (size_t)row * 640 + swz,
                 (char*)Bs + r * 1024);
    }

    // ---- phase 1: aggregation, wave handles nodes [wave*16, wave*16+16)
    for (int q = 0; q < 16; ++q) {
        int m = wave * 16 + q;                 // local row 0..127
        int n = row0 + m;
        int beg = 0, end = 0;
        if (n < N_NODES) {
            beg = n ? offsets[n - 1] : 0;
            end = offsets[n];
        }

        float ax[4] = {0.f, 0.f, 0.f, 0.f};
        float ay[4] = {0.f, 0.f, 0.f, 0.f};
        float at[4] = {0.f, 0.f, 0.f, 0.f};

        int i = beg;
        for (; i + 7 < end; i += 8) {
            unsigned long long p[8];
#pragma unroll
            for (int j = 0; j < 8; ++j) p[j] = ec[i + j];
            unsigned xv[8];
            float tv[8];
#pragma unroll
            for (int j = 0; j < 8; ++j)
                xv[j] = xw[((size_t)(p[j] >> 32) << 6) + lane];
#pragma unroll
            for (int j = 0; j < 8; ++j)
                tv[j] = __builtin_nontemporal_load(tf + ((size_t)(unsigned)p[j] << 6) + lane);
#pragma unroll
            for (int j = 0; j < 8; ++j) {
                ax[j & 3] += bflo(xv[j]);
                ay[j & 3] += bfhi(xv[j]);
                at[j & 3] += tv[j];
            }
        }
        int rem = end - i;                     // 0..7, wave-uniform
        if (rem) {
            int last = end - 1;
            unsigned long long p[8];
#pragma unroll
            for (int j = 0; j < 8; ++j) {
                int idx = i + j;
                if (idx > last) idx = last;
                p[j] = ec[idx];
            }
            unsigned xv[8];
            float tv[8];
#pragma unroll
            for (int j = 0; j < 8; ++j)
                xv[j] = xw[((size_t)(p[j] >> 32) << 6) + lane];
#pragma unroll
            for (int j = 0; j < 8; ++j)
                tv[j] = __builtin_nontemporal_load(tf + ((size_t)(unsigned)p[j] << 6) + lane);
#pragma unroll
            for (int j = 0; j < 8; ++j) {
                if (j < rem) {
                    ax[j & 3] += bflo(xv[j]);
                    ay[j & 3] += bfhi(xv[j]);
                    at[j & 3] += tv[j];
                }
            }
        }

        float fx = (ax[0] + ax[1]) + (ax[2] + ax[3]);
        float fy = (ay[0] + ay[1]) + (ay[2] + ay[3]);
        float ft = (at[0] + at[1]) + (at[2] + at[3]);

        // swizzled LDS writes (byte ^= ((m&7)<<4), i.e. word ^= ((m&7)<<2))
        aggx_lds[m * 64 + (lane >> 5) * 32 + ((lane & 31) ^ ((m & 7) << 2))] =
            pack2(fx, fy);                     // cols 2l, 2l+1
        float pt = __shfl_xor(ft, 1);
        if (!(lane & 1))
            aggt_lds[m * 32 + ((lane >> 1) ^ ((m & 7) << 2))] = pack2(ft, pt);
    }

    __syncthreads();   // drains gathers + chunk-0 staging; agg LDS visible

    // ---- phase 2: MFMA GEMM, wave tile 64x32 (2 M-groups x 4 N-groups)
    int quad = lane >> 4;
    int l16  = lane & 15;
    int mw = (wave >> 2) * 64;
    int nw = (wave & 3) * 32;

    f32x4 acc[4][2];
#pragma unroll
    for (int mt = 0; mt < 4; ++mt)
#pragma unroll
        for (int nt = 0; nt < 2; ++nt)
            acc[mt][nt] = (f32x4){0.f, 0.f, 0.f, 0.f};

    for (int c = 0; c < 5; ++c) {
#pragma unroll
        for (int ks = 0; ks < 2; ++ks) {
            int rb = ((ks * 64 + quad * 16) ^ ((l16 & 7) << 4));
            bf16x8 af[4], bfv[2];
#pragma unroll
            for (int mt = 0; mt < 4; ++mt) {
                int row = mw + mt * 16 + l16;          // row&7 == l16&7
                const char* ap;
                if (c < 2)      ap = (const char*)As + row * 128 + rb;
                else if (c < 4) ap = (const char*)aggx_lds + row * 256 + (c - 2) * 128 + rb;
                else            ap = (const char*)aggt_lds + row * 128 + rb;
                af[mt] = *(const bf16x8*)ap;
            }
#pragma unroll
            for (int nt = 0; nt < 2; ++nt)
                bfv[nt] = *(const bf16x8*)((const char*)Bs + (nw + nt * 16 + l16) * 128 + rb);
#pragma unroll
            for (int mt = 0; mt < 4; ++mt)
#pragma unroll
                for (int nt = 0; nt < 2; ++nt)
                    acc[mt][nt] = __builtin_amdgcn_mfma_f32_16x16x32_bf16(
                        af[mt], bfv[nt], acc[mt][nt], 0, 0, 0);
        }
        if (c < 4) {
            __syncthreads();    // this chunk's LDS reads done
#pragma unroll
            for (int j = 0; j < 2; ++j) {
                int r = wave * 2 + j;
                int row = r * 8 + lr;
                if (c + 1 < 2)
                    gl_lds16((const char*)xb + (size_t)(row0 + row) * 256 +
                                 (size_t)(c + 1) * 128 + swz,
                             (char*)As + r * 1024);
                gl_lds16((const char*)Gtb + (size_t)row * 640 +
                             (size_t)(c + 1) * 128 + swz,
                         (char*)Bs + r * 1024);
            }
            __syncthreads();    // staged data visible
        }
    }

    // ---- epilogue: bias + deg*bias2 + ReLU, nontemporal stores
    float wsb[2], b2[2];
#pragma unroll
    for (int nt = 0; nt < 2; ++nt) {
        int o = nw + nt * 16 + l16;
        wsb[nt] = WSb[o];
        b2[nt]  = bias2[o];
    }
#pragma unroll
    for (int mt = 0; mt < 4; ++mt) {
#pragma unroll
        for (int r = 0; r < 4; ++r) {
            int m = row0 + mw + mt * 16 + quad * 4 + r;
            if (m >= N_NODES) continue;
            float dg = (float)(offsets[m] - (m ? offsets[m - 1] : 0));
#pragma unroll
            for (int nt = 0; nt < 2; ++nt) {
                int o = nw + nt * 16 + l16;
                float val = acc[mt][nt][r] + wsb[nt] + dg * b2[nt];
                __builtin_nontemporal_store(fmaxf(val, 0.f), &out[(size_t)m * 128 + o]);
            }
        }
    }
}

// ---------------------------------------------------------------------------
extern "C" void kernel_launch(void* const* d_in, const int* in_sizes, int n_in,
                              void* d_out, int out_size, void* d_ws, size_t ws_size,
                              hipStream_t stream) {
    const float* x   = (const float*)d_in[0];
    const int*   ei  = (const int*)d_in[1];
    const float* tf  = (const float*)d_in[2];
    const float* WSw = (const float*)d_in[3];
    const float* WSb = (const float*)d_in[4];
    const float* WTw = (const float*)d_in[5];
    const float* WTb = (const float*)d_in[6];
    const float* Tw  = (const float*)d_in[7];
    const float* Tb  = (const float*)d_in[8];
    float* out = (float*)d_out;

    // Workspace layout (~34.5 MB), 16B-aligned blocks first:
    unsigned short* xb  = (unsigned short*)d_ws;                   // M_PAD*128 bf16
    unsigned short* Gtb = xb + (size_t)M_PAD * 128;                // 320*128   bf16
    unsigned long long* ec = (unsigned long long*)(Gtb + (size_t)K_TOT * 128); // 1M u64
    float* bias2 = (float*)(ec + N_EDGES);                         // 128 f
    int* hist    = (int*)(bias2 + 128);                            // 100000 i
    int* offsets = hist + N_NODES;                                 // 100002 i
    int* csum    = offsets + (N_NODES + 2);                        // 128 i

    hipMemsetAsync(hist, 0, (size_t)N_NODES * sizeof(int), stream);

    prep_hist_kernel<<<PREP_BLOCKS + HIST_BLOCKS, 256, 0, stream>>>(
        x, WSw, WTw, Tw, WTb, Tb, xb, Gtb, bias2, ei, hist);

    scan_pass1<<<NCHUNK, 256, 0, stream>>>(hist, csum);
    scan_pass2<<<NCHUNK, 256, 0, stream>>>(hist, csum, offsets);

    fill_kernel<<<(N_EDGES + 255) / 256, 256, 0, stream>>>(ei, offsets, ec);

    agg_gemm_kernel<<<M_PAD / BM, 512, 0, stream>>>(
        tf, ec, offsets, xb, Gtb, WSb, bias2, out);
}